// Round 3
// baseline (118.170 us; speedup 1.0000x reference)
//
#include <hip/hip_runtime.h>

#define NEG_INF (-1e30f)

typedef __bf16 bf16x8 __attribute__((ext_vector_type(8)));
typedef float  f32x4  __attribute__((ext_vector_type(4)));
typedef unsigned short ushort;

__device__ __forceinline__ float fast_tanhf(float x) {
    // 1 - 2/(1+e^{2x}); saturates correctly, ~1e-6 abs err
    return 1.0f - 2.0f / (1.0f + __expf(2.0f * x));
}

__device__ __forceinline__ ushort f2bf(float f) {
    union { float f; unsigned u; } v; v.f = f;
    unsigned r = v.u + 0x7fffu + ((v.u >> 16) & 1u);   // RNE
    return (ushort)(r >> 16);
}

// async global->LDS, 16B per lane, LDS dest = wave-uniform base + lane*16
__device__ __forceinline__ void gload_lds16(const void* gsrc, void* ldsdst) {
    __builtin_amdgcn_global_load_lds(
        (const __attribute__((address_space(1))) unsigned int*)gsrc,
        (__attribute__((address_space(3))) unsigned int*)ldsdst, 16, 0, 0);
}

// ---------------------------------------------------------------------------
// K0: W_sa [H=512][C=512] fp32 -> Wt [C][H] bf16 (transposed, B-frag layout)
// ---------------------------------------------------------------------------
__global__ void convw_kernel(const float* __restrict__ W, ushort* __restrict__ Wt) {
    int i = blockIdx.x * 256 + threadIdx.x;   // 262144
    int h = i >> 9, c = i & 511;
    Wt[c * 512 + h] = f2bf(W[i]);
}

// ---------------------------------------------------------------------------
// K1: m97-style 128x128-tile GEMM + fused tanh*w_sc row-reduce epilogue.
// grid (4 N-blocks, 512 M-blocks), 256 thr / 4 waves (2M x 2N), BK=32.
// Writes score partial per N-block: sp[by*65536 + m].
// ---------------------------------------------------------------------------
__global__ __launch_bounds__(256) void gemm_scores_kernel(
    const float* __restrict__ feat, const ushort* __restrict__ Wt,
    const float* __restrict__ b_sa, const float* __restrict__ w_sc,
    float* __restrict__ sp) {

    __shared__ ushort Alds[128 * 40];   // pitch 40: 2-way bank alias (free)
    __shared__ ushort Blds[128 * 32];   // linear pitch 32 (glds requirement)
    __shared__ float  redE[4][64];

    const int tid  = threadIdx.x;
    const int by   = blockIdx.x;            // N-block 0..3 (fastest: A L2 reuse)
    const int m0   = blockIdx.y * 128;
    const int n0   = by * 128;
    const int lane = tid & 63;
    const int wv   = tid >> 6;
    const int wm   = wv >> 1, wn = wv & 1;  // wave sub-tile (64x64) coords
    const int lr   = lane & 15;
    const int kg   = lane >> 4;
    const int lk   = kg * 8;

    const int arow = tid >> 1;               // 0..127
    const int aseg = (tid & 1) * 16;         // 0 or 16 (floats)
    const float* agp = feat + (size_t)(m0 + arow) * 512 + aseg;

    f32x4 acc[4][4];
#pragma unroll
    for (int a = 0; a < 4; ++a)
#pragma unroll
        for (int b = 0; b < 4; ++b) acc[a][b] = (f32x4){0.f, 0.f, 0.f, 0.f};

    const int o1 = tid + 256;
    const ushort* bg0 = Wt + (size_t)(n0 + (tid >> 2)) * 512 + (tid & 3) * 8;
    const ushort* bg1 = Wt + (size_t)(n0 + (o1 >> 2)) * 512 + (o1 & 3) * 8;

    for (int k0 = 0; k0 < 512; k0 += 32) {
        // issue A global loads early (reg-staged; hides under barrier/stage)
        const float4 v0 = *reinterpret_cast<const float4*>(agp + k0);
        const float4 v1 = *reinterpret_cast<const float4*>(agp + k0 + 4);
        const float4 v2 = *reinterpret_cast<const float4*>(agp + k0 + 8);
        const float4 v3 = *reinterpret_cast<const float4*>(agp + k0 + 12);

        __syncthreads();   // prev iter's ds_reads done before overwrite

        // B: 128x32 bf16 (8 KB) via 2 global_load_lds rounds
        gload_lds16(bg0 + k0, (char*)Blds + wv * 1024);
        gload_lds16(bg1 + k0, (char*)Blds + 4096 + wv * 1024);

        // A: convert fp32->bf16 (compiler emits v_cvt_pk_bf16_f32), 2x b128
        bf16x8 h0, h1;
        h0[0] = (__bf16)v0.x; h0[1] = (__bf16)v0.y; h0[2] = (__bf16)v0.z; h0[3] = (__bf16)v0.w;
        h0[4] = (__bf16)v1.x; h0[5] = (__bf16)v1.y; h0[6] = (__bf16)v1.z; h0[7] = (__bf16)v1.w;
        h1[0] = (__bf16)v2.x; h1[1] = (__bf16)v2.y; h1[2] = (__bf16)v2.z; h1[3] = (__bf16)v2.w;
        h1[4] = (__bf16)v3.x; h1[5] = (__bf16)v3.y; h1[6] = (__bf16)v3.z; h1[7] = (__bf16)v3.w;
        *reinterpret_cast<bf16x8*>(&Alds[arow * 40 + aseg]) = h0;
        *reinterpret_cast<bf16x8*>(&Alds[arow * 40 + aseg + 8]) = h1;

        __syncthreads();   // compiler drains vmcnt+lgkmcnt here

        bf16x8 af[4], bfv[4];
#pragma unroll
        for (int a = 0; a < 4; ++a)
            af[a] = *reinterpret_cast<const bf16x8*>(
                &Alds[(wm * 64 + a * 16 + lr) * 40 + lk]);   // FIX: + wm*64
#pragma unroll
        for (int b = 0; b < 4; ++b)
            bfv[b] = *reinterpret_cast<const bf16x8*>(&Blds[(wn * 64 + b * 16 + lr) * 32 + lk]);
#pragma unroll
        for (int a = 0; a < 4; ++a)
#pragma unroll
            for (int b = 0; b < 4; ++b)
                acc[a][b] = __builtin_amdgcn_mfma_f32_16x16x32_bf16(
                    af[a], bfv[b], acc[a][b], 0, 0, 0);
    }

    // Epilogue: per-row sum over this block's 128 cols of tanh(C+b_sa)*w_sc
    float rsum[4][4];
#pragma unroll
    for (int a = 0; a < 4; ++a)
#pragma unroll
        for (int r = 0; r < 4; ++r) rsum[a][r] = 0.0f;

#pragma unroll
    for (int b = 0; b < 4; ++b) {
        int col = n0 + wn * 64 + b * 16 + lr;
        float wsc = w_sc[col];
        float bsa = b_sa[col];
#pragma unroll
        for (int a = 0; a < 4; ++a)
#pragma unroll
            for (int r = 0; r < 4; ++r)
                rsum[a][r] += fast_tanhf(acc[a][b][r] + bsa) * wsc;
    }
#pragma unroll
    for (int a = 0; a < 4; ++a)
#pragma unroll
        for (int r = 0; r < 4; ++r) {
            float v = rsum[a][r];
            v += __shfl_xor(v, 1);
            v += __shfl_xor(v, 2);
            v += __shfl_xor(v, 4);
            v += __shfl_xor(v, 8);
            rsum[a][r] = v;
        }
    if (lr == 0) {
        // wave wv's rows are global rows wm*64 + (a*16 + kg*4 + r)
#pragma unroll
        for (int a = 0; a < 4; ++a)
#pragma unroll
            for (int r = 0; r < 4; ++r)
                redE[wv][a * 16 + kg * 4 + r] = rsum[a][r];
    }
    __syncthreads();
    if (tid < 128) {
        int wmo = tid >> 6, r64 = tid & 63;   // rows 0..63 from waves 0,1; 64..127 from 2,3
        sp[(size_t)by * 65536 + m0 + tid] = redE[wmo * 2][r64] + redE[wmo * 2 + 1][r64];
    }
}

// ---------------------------------------------------------------------------
// K2: combine 4 partials + b_sc + mask, per-batch masked softmax -> probs
// ---------------------------------------------------------------------------
__global__ void softmax_kernel(const float* __restrict__ sp, const float* __restrict__ b_sc,
                               const int* __restrict__ mask, float* __restrict__ probs) {
    int b = blockIdx.x, t = threadIdx.x;  // 256 threads
    int i0 = b * 512 + t, i1 = i0 + 256;
    float s0 = sp[i0] + sp[65536 + i0] + sp[131072 + i0] + sp[196608 + i0] + b_sc[0];
    float s1 = sp[i1] + sp[65536 + i1] + sp[131072 + i1] + sp[196608 + i1] + b_sc[0];
    if (!mask[i0]) s0 = NEG_INF;
    if (!mask[i1]) s1 = NEG_INF;
    float m = fmaxf(s0, s1);
#pragma unroll
    for (int o = 1; o < 64; o <<= 1) m = fmaxf(m, __shfl_xor(m, o));
    __shared__ float red[4];
    if ((t & 63) == 0) red[t >> 6] = m;
    __syncthreads();
    m = fmaxf(fmaxf(red[0], red[1]), fmaxf(red[2], red[3]));
    float e0 = __expf(s0 - m), e1 = __expf(s1 - m);
    float z = e0 + e1;
#pragma unroll
    for (int o = 1; o < 64; o <<= 1) z += __shfl_xor(z, o);
    __syncthreads();
    if ((t & 63) == 0) red[t >> 6] = z;
    __syncthreads();
    float inv = 1.0f / (red[0] + red[1] + red[2] + red[3]);
    probs[i0] = e0 * inv;
    probs[i1] = e1 * inv;
}

// ---------------------------------------------------------------------------
// K3: pooled partial: block (b, c): rows [c*128, c*128+128), float4 cols.
// 256 thr = 128 col4-groups x 2 row-stripes of 64.
// ---------------------------------------------------------------------------
__global__ void pool_kernel(const float* __restrict__ feat,
                            const float* __restrict__ probs,
                            float* __restrict__ part) {
    int b = blockIdx.x, c = blockIdx.y, t = threadIdx.x;
    __shared__ float pl[128];
    __shared__ float red2[2][512];
    if (t < 128) pl[t] = probs[b * 512 + c * 128 + t];
    __syncthreads();
    int col4 = (t & 127) * 4;
    int stripe = t >> 7;
    const float* fb = feat + ((size_t)(b * 512 + c * 128 + stripe * 64)) * 512 + col4;
    float4 a4 = {0.f, 0.f, 0.f, 0.f};
#pragma unroll 8
    for (int n = 0; n < 64; ++n) {
        float p = pl[stripe * 64 + n];
        const float4 f4 = *reinterpret_cast<const float4*>(fb + (size_t)n * 512);
        a4.x = fmaf(p, f4.x, a4.x);
        a4.y = fmaf(p, f4.y, a4.y);
        a4.z = fmaf(p, f4.z, a4.z);
        a4.w = fmaf(p, f4.w, a4.w);
    }
    *reinterpret_cast<float4*>(&red2[stripe][col4]) = a4;
    __syncthreads();
    // 512 cols, 256 threads: 2 cols each
    float x0 = red2[0][t] + red2[1][t];
    float x1 = red2[0][t + 256] + red2[1][t + 256];
    part[(size_t)c * 65536 + b * 512 + t]       = x0;
    part[(size_t)c * 65536 + b * 512 + t + 256] = x1;
}

// ---------------------------------------------------------------------------
// K4: out = tanh(sum of 4 partials)
// ---------------------------------------------------------------------------
__global__ void finish_kernel(const float* __restrict__ part, float* __restrict__ out) {
    int i = blockIdx.x * 256 + threadIdx.x;
    float s = part[i] + part[65536 + i] + part[131072 + i] + part[196608 + i];
    out[i] = fast_tanhf(s);
}

extern "C" void kernel_launch(void* const* d_in, const int* in_sizes, int n_in,
                              void* d_out, int out_size, void* d_ws, size_t ws_size,
                              hipStream_t stream) {
    const float* feat = (const float*)d_in[0];
    const int*   mask = (const int*)d_in[1];
    const float* W_sa = (const float*)d_in[2];
    const float* b_sa = (const float*)d_in[3];
    const float* w_sc = (const float*)d_in[4];
    const float* b_sc = (const float*)d_in[5];
    float* out = (float*)d_out;

    char* ws = (char*)d_ws;
    ushort* Wt    = (ushort*)ws;                               // 512 KB
    float*  sp    = (float*)(ws + (512 << 10));                // 1 MB  (4 x 65536)
    float*  probs = (float*)(ws + (512 << 10) + (1024 << 10)); // 256 KB
    float*  part  = (float*)(ws + (512 << 10) + (1280 << 10)); // 1 MB  (4 x 65536)

    hipLaunchKernelGGL(convw_kernel, dim3(1024), dim3(256), 0, stream, W_sa, Wt);
    hipLaunchKernelGGL(gemm_scores_kernel, dim3(4, 512), dim3(256), 0, stream,
                       feat, Wt, b_sa, w_sc, sp);
    hipLaunchKernelGGL(softmax_kernel, dim3(128), dim3(256), 0, stream,
                       sp, b_sc, mask, probs);
    hipLaunchKernelGGL(pool_kernel, dim3(128, 4), dim3(256), 0, stream, feat, probs, part);
    hipLaunchKernelGGL(finish_kernel, dim3(256), dim3(256), 0, stream, part, out);
}

// Round 4
// 107.360 us; speedup vs baseline: 1.1007x; 1.1007x over previous
//
#include <hip/hip_runtime.h>

#define NEG_INF (-1e30f)

typedef __bf16 bf16x8 __attribute__((ext_vector_type(8)));
typedef float  f32x4  __attribute__((ext_vector_type(4)));
typedef unsigned short ushort;

__device__ __forceinline__ float fast_tanhf(float x) {
    return 1.0f - 2.0f / (1.0f + __expf(2.0f * x));
}

__device__ __forceinline__ ushort f2bf(float f) {
    union { float f; unsigned u; } v; v.f = f;
    unsigned r = v.u + 0x7fffu + ((v.u >> 16) & 1u);   // RNE
    return (ushort)(r >> 16);
}

// async global->LDS, 16B/lane, LDS dest = wave-uniform base + lane*16
__device__ __forceinline__ void gload_lds16(const void* gsrc, void* ldsdst) {
    __builtin_amdgcn_global_load_lds(
        (const __attribute__((address_space(1))) unsigned int*)gsrc,
        (__attribute__((address_space(3))) unsigned int*)ldsdst, 16, 0, 0);
}

// ---------------------------------------------------------------------------
// K0: W_sa [H=512][C=512] fp32 -> Wt [C][H] bf16 (transposed)
// ---------------------------------------------------------------------------
__global__ void convw_kernel(const float* __restrict__ W, ushort* __restrict__ Wt) {
    int i = blockIdx.x * 256 + threadIdx.x;
    int h = i >> 9, c = i & 511;
    Wt[c * 512 + h] = f2bf(W[i]);
}

// ---------------------------------------------------------------------------
// K1: 128x128-tile GEMM, 2-phase pipelined (T3-min), blocked LDS layout,
// fused tanh*w_sc row-reduce epilogue. Flat grid 2048, XCD-aware decomp:
// xcd = id&7 owns M-panels [xcd*64, xcd*64+64), 4 consecutive blocks = the
// 4 N-chunks of one panel (A fetched once per XCD, L2-hot).
// LDS tile layout (both A and B): ushort idx = (r>>4)*512 + kseg*128 + (r&15)*8
// -> every ds_read_b128 is 16 lanes x 256 contiguous bytes (2-way, free).
// ---------------------------------------------------------------------------
__global__ __launch_bounds__(256) void gemm_scores_kernel(
    const float* __restrict__ feat, const ushort* __restrict__ Wt,
    const float* __restrict__ b_sa, const float* __restrict__ w_sc,
    float* __restrict__ sp) {

    __shared__ ushort Alds[2][4096];
    __shared__ ushort Blds[2][4096];
    __shared__ float  redE[4][64];

    const int tid  = threadIdx.x;
    const int id   = blockIdx.x;
    const int g    = id & 7;                 // XCD (round-robin dispatch)
    const int c8   = id >> 3;                // 0..255
    const int my   = g * 64 + (c8 >> 2);     // M-panel 0..511
    const int by   = c8 & 3;                 // N-chunk 0..3
    const int m0   = my * 128;
    const int n0   = by * 128;

    const int lane = tid & 63;
    const int wv   = tid >> 6;
    const int wm   = wv >> 1, wn = wv & 1;   // 2M x 2N wave grid (64x64 each)
    const int lr   = lane & 15;
    const int kg   = lane >> 4;

    // A global-load geometry: thread -> (row, 16-float segment)
    const int arow = tid >> 1;               // 0..127
    const int aseg = (tid & 1) * 16;         // 0 or 16 (floats)
    const float* agp = feat + (size_t)(m0 + arow) * 512 + aseg;
    // A ds_write index (blocked layout), loop-invariant
    const int wA = (arow >> 4) * 512 + (aseg >> 3) * 128 + (arow & 15) * 8;

    // B glds source: instr i, wave wv covers cols (i*4+wv)*16 + (lane&15),
    // kseg = lane>>4 (dest = linear chunk (i*4+wv)*1024 + lane*16)
    const ushort* bg0 = Wt + (size_t)(n0 + (0 * 4 + wv) * 16 + lr) * 512 + kg * 8;
    const ushort* bg1 = Wt + (size_t)(n0 + (1 * 4 + wv) * 16 + lr) * 512 + kg * 8;

    // frag read bases (blocked layout)
    const int aBase = wm * 2048 + kg * 128 + lr * 8;
    const int bBase = wn * 2048 + kg * 128 + lr * 8;

    f32x4 acc[4][4];
#pragma unroll
    for (int a = 0; a < 4; ++a)
#pragma unroll
        for (int b = 0; b < 4; ++b) acc[a][b] = (f32x4){0.f, 0.f, 0.f, 0.f};

    // ---- prologue: stage tile 0, prefetch A(tile 1) ----
    float4 p0 = *reinterpret_cast<const float4*>(agp + 0);
    float4 p1 = *reinterpret_cast<const float4*>(agp + 4);
    float4 p2 = *reinterpret_cast<const float4*>(agp + 8);
    float4 p3 = *reinterpret_cast<const float4*>(agp + 12);
    gload_lds16(bg0, (char*)Blds[0] + wv * 1024);
    gload_lds16(bg1, (char*)Blds[0] + 4096 + wv * 1024);
    {
        bf16x8 h0, h1;
        h0[0] = (__bf16)p0.x; h0[1] = (__bf16)p0.y; h0[2] = (__bf16)p0.z; h0[3] = (__bf16)p0.w;
        h0[4] = (__bf16)p1.x; h0[5] = (__bf16)p1.y; h0[6] = (__bf16)p1.z; h0[7] = (__bf16)p1.w;
        h1[0] = (__bf16)p2.x; h1[1] = (__bf16)p2.y; h1[2] = (__bf16)p2.z; h1[3] = (__bf16)p2.w;
        h1[4] = (__bf16)p3.x; h1[5] = (__bf16)p3.y; h1[6] = (__bf16)p3.z; h1[7] = (__bf16)p3.w;
        *reinterpret_cast<bf16x8*>(&Alds[0][wA])       = h0;
        *reinterpret_cast<bf16x8*>(&Alds[0][wA + 128]) = h1;
    }
    p0 = *reinterpret_cast<const float4*>(agp + 32);
    p1 = *reinterpret_cast<const float4*>(agp + 36);
    p2 = *reinterpret_cast<const float4*>(agp + 40);
    p3 = *reinterpret_cast<const float4*>(agp + 44);
    __syncthreads();   // drains vmcnt (glds B0, A-prefetch) + lgkm (A writes)

    int p = 0;
    for (int k0 = 0; k0 < 512; k0 += 32) {
        // ---- STAGE tile t+1 into buf[p^1] ----
        if (k0 < 480) {
            bf16x8 h0, h1;
            h0[0] = (__bf16)p0.x; h0[1] = (__bf16)p0.y; h0[2] = (__bf16)p0.z; h0[3] = (__bf16)p0.w;
            h0[4] = (__bf16)p1.x; h0[5] = (__bf16)p1.y; h0[6] = (__bf16)p1.z; h0[7] = (__bf16)p1.w;
            h1[0] = (__bf16)p2.x; h1[1] = (__bf16)p2.y; h1[2] = (__bf16)p2.z; h1[3] = (__bf16)p2.w;
            h1[4] = (__bf16)p3.x; h1[5] = (__bf16)p3.y; h1[6] = (__bf16)p3.z; h1[7] = (__bf16)p3.w;
            *reinterpret_cast<bf16x8*>(&Alds[p ^ 1][wA])       = h0;
            *reinterpret_cast<bf16x8*>(&Alds[p ^ 1][wA + 128]) = h1;
            gload_lds16(bg0 + k0 + 32, (char*)Blds[p ^ 1] + wv * 1024);
            gload_lds16(bg1 + k0 + 32, (char*)Blds[p ^ 1] + 4096 + wv * 1024);
            if (k0 < 448) {   // prefetch A(tile t+2) into regs
                p0 = *reinterpret_cast<const float4*>(agp + k0 + 64);
                p1 = *reinterpret_cast<const float4*>(agp + k0 + 68);
                p2 = *reinterpret_cast<const float4*>(agp + k0 + 72);
                p3 = *reinterpret_cast<const float4*>(agp + k0 + 76);
            }
        }
        // ---- compute tile t from buf[p] ----
        bf16x8 af[4], bfv[4];
#pragma unroll
        for (int a = 0; a < 4; ++a)
            af[a] = *reinterpret_cast<const bf16x8*>(&Alds[p][aBase + a * 512]);
#pragma unroll
        for (int b = 0; b < 4; ++b)
            bfv[b] = *reinterpret_cast<const bf16x8*>(&Blds[p][bBase + b * 512]);
#pragma unroll
        for (int a = 0; a < 4; ++a)
#pragma unroll
            for (int b = 0; b < 4; ++b)
                acc[a][b] = __builtin_amdgcn_mfma_f32_16x16x32_bf16(
                    af[a], bfv[b], acc[a][b], 0, 0, 0);
        __syncthreads();   // one full drain + barrier per K-tile
        p ^= 1;
    }

    // ---- epilogue: rsum over this block's 128 cols of tanh(C+b_sa)*w_sc ----
    float rsum[4][4];
#pragma unroll
    for (int a = 0; a < 4; ++a)
#pragma unroll
        for (int r = 0; r < 4; ++r) rsum[a][r] = 0.0f;

#pragma unroll
    for (int b = 0; b < 4; ++b) {
        int col = n0 + wn * 64 + b * 16 + lr;
        float wsc = w_sc[col];
        float bsa = b_sa[col];
#pragma unroll
        for (int a = 0; a < 4; ++a)
#pragma unroll
            for (int r = 0; r < 4; ++r)
                rsum[a][r] += fast_tanhf(acc[a][b][r] + bsa) * wsc;
    }
#pragma unroll
    for (int a = 0; a < 4; ++a)
#pragma unroll
        for (int r = 0; r < 4; ++r) {
            float v = rsum[a][r];
            v += __shfl_xor(v, 1);
            v += __shfl_xor(v, 2);
            v += __shfl_xor(v, 4);
            v += __shfl_xor(v, 8);
            rsum[a][r] = v;
        }
    if (lr == 0) {
#pragma unroll
        for (int a = 0; a < 4; ++a)
#pragma unroll
            for (int r = 0; r < 4; ++r)
                redE[wv][a * 16 + kg * 4 + r] = rsum[a][r];
    }
    __syncthreads();
    if (tid < 128) {
        int wmo = tid >> 6, r64 = tid & 63;
        sp[(size_t)by * 65536 + m0 + tid] = redE[wmo * 2][r64] + redE[wmo * 2 + 1][r64];
    }
}

// ---------------------------------------------------------------------------
// K2: combine 4 partials + b_sc + mask, per-batch masked softmax -> probs
// ---------------------------------------------------------------------------
__global__ void softmax_kernel(const float* __restrict__ sp, const float* __restrict__ b_sc,
                               const int* __restrict__ mask, float* __restrict__ probs) {
    int b = blockIdx.x, t = threadIdx.x;
    int i0 = b * 512 + t, i1 = i0 + 256;
    float s0 = sp[i0] + sp[65536 + i0] + sp[131072 + i0] + sp[196608 + i0] + b_sc[0];
    float s1 = sp[i1] + sp[65536 + i1] + sp[131072 + i1] + sp[196608 + i1] + b_sc[0];
    if (!mask[i0]) s0 = NEG_INF;
    if (!mask[i1]) s1 = NEG_INF;
    float m = fmaxf(s0, s1);
#pragma unroll
    for (int o = 1; o < 64; o <<= 1) m = fmaxf(m, __shfl_xor(m, o));
    __shared__ float red[4];
    if ((t & 63) == 0) red[t >> 6] = m;
    __syncthreads();
    m = fmaxf(fmaxf(red[0], red[1]), fmaxf(red[2], red[3]));
    float e0 = __expf(s0 - m), e1 = __expf(s1 - m);
    float z = e0 + e1;
#pragma unroll
    for (int o = 1; o < 64; o <<= 1) z += __shfl_xor(z, o);
    __syncthreads();
    if ((t & 63) == 0) red[t >> 6] = z;
    __syncthreads();
    float inv = 1.0f / (red[0] + red[1] + red[2] + red[3]);
    probs[i0] = e0 * inv;
    probs[i1] = e1 * inv;
}

// ---------------------------------------------------------------------------
// K3: pooled partial: block (b, c): rows [c*128, c*128+128), float4 cols
// ---------------------------------------------------------------------------
__global__ void pool_kernel(const float* __restrict__ feat,
                            const float* __restrict__ probs,
                            float* __restrict__ part) {
    int b = blockIdx.x, c = blockIdx.y, t = threadIdx.x;
    __shared__ float pl[128];
    __shared__ float red2[2][512];
    if (t < 128) pl[t] = probs[b * 512 + c * 128 + t];
    __syncthreads();
    int col4 = (t & 127) * 4;
    int stripe = t >> 7;
    const float* fb = feat + ((size_t)(b * 512 + c * 128 + stripe * 64)) * 512 + col4;
    float4 a4 = {0.f, 0.f, 0.f, 0.f};
#pragma unroll 8
    for (int n = 0; n < 64; ++n) {
        float p = pl[stripe * 64 + n];
        const float4 f4 = *reinterpret_cast<const float4*>(fb + (size_t)n * 512);
        a4.x = fmaf(p, f4.x, a4.x);
        a4.y = fmaf(p, f4.y, a4.y);
        a4.z = fmaf(p, f4.z, a4.z);
        a4.w = fmaf(p, f4.w, a4.w);
    }
    *reinterpret_cast<float4*>(&red2[stripe][col4]) = a4;
    __syncthreads();
    float x0 = red2[0][t] + red2[1][t];
    float x1 = red2[0][t + 256] + red2[1][t + 256];
    part[(size_t)c * 65536 + b * 512 + t]       = x0;
    part[(size_t)c * 65536 + b * 512 + t + 256] = x1;
}

// ---------------------------------------------------------------------------
// K4: out = tanh(sum of 4 partials)
// ---------------------------------------------------------------------------
__global__ void finish_kernel(const float* __restrict__ part, float* __restrict__ out) {
    int i = blockIdx.x * 256 + threadIdx.x;
    float s = part[i] + part[65536 + i] + part[131072 + i] + part[196608 + i];
    out[i] = fast_tanhf(s);
}

extern "C" void kernel_launch(void* const* d_in, const int* in_sizes, int n_in,
                              void* d_out, int out_size, void* d_ws, size_t ws_size,
                              hipStream_t stream) {
    const float* feat = (const float*)d_in[0];
    const int*   mask = (const int*)d_in[1];
    const float* W_sa = (const float*)d_in[2];
    const float* b_sa = (const float*)d_in[3];
    const float* w_sc = (const float*)d_in[4];
    const float* b_sc = (const float*)d_in[5];
    float* out = (float*)d_out;

    char* ws = (char*)d_ws;
    ushort* Wt    = (ushort*)ws;                               // 512 KB
    float*  sp    = (float*)(ws + (512 << 10));                // 1 MB (4 x 65536)
    float*  probs = (float*)(ws + (512 << 10) + (1024 << 10)); // 256 KB
    float*  part  = (float*)(ws + (512 << 10) + (1280 << 10)); // 1 MB (4 x 65536)

    hipLaunchKernelGGL(convw_kernel, dim3(1024), dim3(256), 0, stream, W_sa, Wt);
    hipLaunchKernelGGL(gemm_scores_kernel, dim3(2048), dim3(256), 0, stream,
                       feat, Wt, b_sa, w_sc, sp);
    hipLaunchKernelGGL(softmax_kernel, dim3(128), dim3(256), 0, stream,
                       sp, b_sc, mask, probs);
    hipLaunchKernelGGL(pool_kernel, dim3(128, 4), dim3(256), 0, stream, feat, probs, part);
    hipLaunchKernelGGL(finish_kernel, dim3(256), dim3(256), 0, stream, part, out);
}